// Round 1
// 693.952 us; speedup vs baseline: 1.0675x; 1.0675x over previous
//
#include <hip/hip_runtime.h>
#include <stdint.h>

// ---------------------------------------------------------------------------
// LayerNormDenseGeneral: y = LN(x)*scale+bias; z = y @ W.  Outputs (z, y).
// Shapes: x[S,B,H]=[2048,4,2048] fp32, W[H,F]=[2048,8192] fp32.
// Round 3: GEMM upgraded from m97-structure (128^2, vmcnt-drain per K-step,
// 733 TF / MfmaUtil 34%) to 256^2 / BK=64 / 8-wave phase-interleaved schedule
// with counted vmcnt(8) that never drains to 0 in the main loop (T3+T4),
// setprio around MFMA clusters (T5), XOR-swizzled conflict-free LDS (T2),
// XCD-aware block swizzle (T1). LN + transpose kernels kept byte-identical
// for counter isolation.
// ws layout: [0, M*K*2) = A bf16 ; [M*K*2, M*K*2 + F*K*2) = Bt bf16. 64 MiB.
// ---------------------------------------------------------------------------

typedef __attribute__((ext_vector_type(8))) short short8;   // 8 x bf16 bits
typedef __attribute__((ext_vector_type(4))) float floatx4;  // MFMA acc

__device__ __forceinline__ unsigned short f2bf(float f) {
    unsigned u = __builtin_bit_cast(unsigned, f);
    u += 0x7fffu + ((u >> 16) & 1u);   // round-to-nearest-even
    return (unsigned short)(u >> 16);
}

// ---------------- LayerNorm: one block per row, H=2048 ---------------------
__global__ __launch_bounds__(256) void ln_kernel(
    const float* __restrict__ x, const float* __restrict__ scale,
    const float* __restrict__ bias, float* __restrict__ y,
    unsigned short* __restrict__ ybf, int H)
{
    const int row = blockIdx.x;
    const float* xr = x + (size_t)row * H;
    const int tid = threadIdx.x;

    // H = 2048: each thread handles float4 at [tid] and [tid+256]
    float4 v0 = ((const float4*)xr)[tid];
    float4 v1 = ((const float4*)xr)[tid + 256];

    float s  = v0.x + v0.y + v0.z + v0.w + v1.x + v1.y + v1.z + v1.w;
    float ss = v0.x*v0.x + v0.y*v0.y + v0.z*v0.z + v0.w*v0.w
             + v1.x*v1.x + v1.y*v1.y + v1.z*v1.z + v1.w*v1.w;

    // wave(64) reduce
    #pragma unroll
    for (int off = 32; off > 0; off >>= 1) {
        s  += __shfl_down(s,  off, 64);
        ss += __shfl_down(ss, off, 64);
    }
    __shared__ float rs[4], rq[4];
    if ((tid & 63) == 0) { rs[tid >> 6] = s; rq[tid >> 6] = ss; }
    __syncthreads();
    float ts = rs[0] + rs[1] + rs[2] + rs[3];
    float tq = rq[0] + rq[1] + rq[2] + rq[3];
    float mean = ts / (float)H;
    float var  = tq / (float)H - mean * mean;
    float rstd = rsqrtf(var + 1e-6f);

    float4 sc0 = ((const float4*)scale)[tid];
    float4 sc1 = ((const float4*)scale)[tid + 256];
    float4 b0  = ((const float4*)bias)[tid];
    float4 b1  = ((const float4*)bias)[tid + 256];

    float4 o0, o1;
    o0.x = (v0.x - mean) * rstd * sc0.x + b0.x;
    o0.y = (v0.y - mean) * rstd * sc0.y + b0.y;
    o0.z = (v0.z - mean) * rstd * sc0.z + b0.z;
    o0.w = (v0.w - mean) * rstd * sc0.w + b0.w;
    o1.x = (v1.x - mean) * rstd * sc1.x + b1.x;
    o1.y = (v1.y - mean) * rstd * sc1.y + b1.y;
    o1.z = (v1.z - mean) * rstd * sc1.z + b1.z;
    o1.w = (v1.w - mean) * rstd * sc1.w + b1.w;

    float* yr = y + (size_t)row * H;
    ((float4*)yr)[tid]       = o0;
    ((float4*)yr)[tid + 256] = o1;

    unsigned short* br = ybf + (size_t)row * H;
    uint2 p0, p1;
    p0.x = (unsigned)f2bf(o0.x) | ((unsigned)f2bf(o0.y) << 16);
    p0.y = (unsigned)f2bf(o0.z) | ((unsigned)f2bf(o0.w) << 16);
    p1.x = (unsigned)f2bf(o1.x) | ((unsigned)f2bf(o1.y) << 16);
    p1.y = (unsigned)f2bf(o1.z) | ((unsigned)f2bf(o1.w) << 16);
    ((uint2*)br)[tid]       = p0;
    ((uint2*)br)[tid + 256] = p1;
}

// -------- transpose-cast: W[K][F] fp32 -> Bt[F][K] bf16, 64x64 tiles -------
__global__ __launch_bounds__(256) void transpose_cast_kernel(
    const float* __restrict__ W, unsigned short* __restrict__ Bt,
    int K, int F)
{
    __shared__ float tile[64][65];
    const int kBase = blockIdx.y * 64;
    const int fBase = blockIdx.x * 64;
    const int tid = threadIdx.x;

    // read: 4 passes x (16 rows of 64 floats), coalesced float4
    #pragma unroll
    for (int p = 0; p < 4; ++p) {
        int kl = (tid >> 4) + p * 16;
        int fl = (tid & 15) * 4;
        float4 v = *(const float4*)&W[(size_t)(kBase + kl) * F + fBase + fl];
        tile[kl][fl]     = v.x;
        tile[kl][fl + 1] = v.y;
        tile[kl][fl + 2] = v.z;
        tile[kl][fl + 3] = v.w;
    }
    __syncthreads();

    // write: 2 passes x (32 f-rows), each thread packs 8 bf16 = 16B store
    #pragma unroll
    for (int p = 0; p < 2; ++p) {
        int fl = (tid >> 3) + p * 32;
        int k8 = (tid & 7) * 8;
        unsigned w[4];
        #pragma unroll
        for (int j = 0; j < 4; ++j) {
            unsigned lo = f2bf(tile[k8 + 2*j][fl]);
            unsigned hi = f2bf(tile[k8 + 2*j + 1][fl]);
            w[j] = lo | (hi << 16);
        }
        uint4 out = make_uint4(w[0], w[1], w[2], w[3]);
        *(uint4*)&Bt[(size_t)(fBase + fl) * K + kBase + k8] = out;
    }
}

// ---------------- GEMM: C[M][N] = A[M][K] * Bt[N][K]^T (bf16 -> fp32) ------
// 256x256 tile, BK=64, 512 threads = 8 waves (2M x 4N), wave tile 128x64.
// LDS 128 KiB: lds[buf][op][khalf][256 rows x 4 chunks x 8 shorts].
// Each k-half block is 16 KiB contiguous so global_load_lds dest stays linear
// (base + lane*16). Swizzle: chunk c of row r stored at slot c ^ ((r>>2)&3);
// inverse XOR applied to the per-lane GLOBAL source address, same XOR on the
// ds_read side -> conflict-free (8 bank-quads x 2 lanes per 16-lane group).
//
// Phase schedule (per K-tile t, buf p = t&1; one barrier per phase):
//   phase A: issue stage (t+1).kh1 -> buf[p^1]; read kh0 frags; 32 MFMA;
//            vmcnt(8)  [retires (t).kh1 needed by phase B]; s_barrier
//   phase B: issue stage (t+2).kh0 -> buf[p];   read kh1 frags; 32 MFMA;
//            vmcnt(8)  [retires (t+1).kh0 needed by next A]; s_barrier
// Steady state: 8 loads (2 half-K-tile groups) stay in flight across every
// barrier — never drained to 0 (m218's lever). Tail clamps the prefetch
// SOURCE tile; clamped stages write buffers that are never read again.
#define GBM 256
#define GBN 256
#define GBK 64

__device__ __forceinline__ void stage_half(
    const unsigned short* __restrict__ gA,   // A  + tileM*256*K
    const unsigned short* __restrict__ gB,   // Bt + tileN*256*K
    unsigned short* dstA,                    // &lds[p][0][kh][0]
    unsigned short* dstB,                    // &lds[p][1][kh][0]
    int t, int kh, int K, int tid)
{
    const size_t kb = (size_t)t * GBK + (size_t)kh * 32;
    // 1024 chunks of 16B per operand half: e = row*4 + slot
    #pragma unroll
    for (int i = 0; i < 2; ++i) {
        int e  = i * 512 + tid;
        int r  = e >> 2;
        int c2 = (e & 3) ^ ((r >> 2) & 3);   // inverse swizzle on global src
        __builtin_amdgcn_global_load_lds(
            (const __attribute__((address_space(1))) unsigned int*)
                (gA + (size_t)r * K + kb + c2 * 8),
            (__attribute__((address_space(3))) unsigned int*)(dstA + e * 8),
            16, 0, 0);
    }
    #pragma unroll
    for (int i = 0; i < 2; ++i) {
        int e  = i * 512 + tid;
        int r  = e >> 2;
        int c2 = (e & 3) ^ ((r >> 2) & 3);
        __builtin_amdgcn_global_load_lds(
            (const __attribute__((address_space(1))) unsigned int*)
                (gB + (size_t)r * K + kb + c2 * 8),
            (__attribute__((address_space(3))) unsigned int*)(dstB + e * 8),
            16, 0, 0);
    }
}

__device__ __forceinline__ void compute_phase(
    const unsigned short* bufA,              // &lds[p][0][kh][0]
    const unsigned short* bufB,              // &lds[p][1][kh][0]
    floatx4 (&acc)[8][4],
    int waveM, int waveN, int quad, int l16, int sl)
{
    short8 a[8], b[4];
    #pragma unroll
    for (int mi = 0; mi < 8; ++mi) {
        int r = waveM * 128 + mi * 16 + l16;
        a[mi] = *(const short8*)(bufA + ((size_t)r * 4 + sl) * 8);
    }
    #pragma unroll
    for (int ni = 0; ni < 4; ++ni) {
        int r = waveN * 64 + ni * 16 + l16;
        b[ni] = *(const short8*)(bufB + ((size_t)r * 4 + sl) * 8);
    }
    __builtin_amdgcn_s_setprio(1);
    #pragma unroll
    for (int mi = 0; mi < 8; ++mi)
        #pragma unroll
        for (int ni = 0; ni < 4; ++ni)
            acc[mi][ni] = __builtin_amdgcn_mfma_f32_16x16x32_bf16(
                a[mi], b[ni], acc[mi][ni], 0, 0, 0);
    __builtin_amdgcn_s_setprio(0);
}

__global__ __launch_bounds__(512, 2) void gemm_bf16_8w(
    const unsigned short* __restrict__ A,   // [M][K] bf16
    const unsigned short* __restrict__ Bt,  // [N][K] bf16
    float* __restrict__ C,                  // [M][N] fp32
    int M, int N, int K)
{
    __shared__ __align__(128) unsigned short lds[2][2][2][8192]; // 128 KiB

    const int tid   = threadIdx.x;
    const int lane  = tid & 63;
    const int wave  = tid >> 6;     // 0..7
    const int waveM = wave >> 2;    // 0..1
    const int waveN = wave & 3;     // 0..3
    const int quad  = lane >> 4;    // 0..3
    const int l16   = lane & 15;
    const int sl    = quad ^ (l16 >> 2);   // read-side swizzled slot (0..3)

    // XCD-aware bijective swizzle (nwg = 1024, divisible by 8)
    const int nwg = gridDim.x;
    const int cpx = nwg >> 3;
    const int bid = blockIdx.x;
    const int wg  = (bid & 7) * cpx + (bid >> 3);
    const int tilesN = N >> 8;
    const int tm = wg / tilesN;
    const int tn = wg % tilesN;

    const unsigned short* gA = A  + (size_t)tm * GBM * K;
    const unsigned short* gB = Bt + (size_t)tn * GBN * K;

    const int NTt = K >> 6;         // K-tiles of 64

    floatx4 acc[8][4] = {};

    // prologue: tile0 (both halves) + tile1.kh0; keep tile0.kh1 + tile1.kh0
    // in flight across the first barrier
    stage_half(gA, gB, &lds[0][0][0][0], &lds[0][1][0][0], 0, 0, K, tid);
    stage_half(gA, gB, &lds[0][0][1][0], &lds[0][1][1][0], 0, 1, K, tid);
    stage_half(gA, gB, &lds[1][0][0][0], &lds[1][1][0][0], 1, 0, K, tid);
    asm volatile("s_waitcnt vmcnt(8)" ::: "memory");  // tile0.kh0 resident
    __builtin_amdgcn_s_barrier();

    for (int t = 0; t < NTt; ++t) {
        const int p = t & 1;
        {   // phase A: compute kh0 of tile t; prefetch (t+1).kh1
            int ts = (t + 1 < NTt) ? (t + 1) : (NTt - 1);
            stage_half(gA, gB, &lds[p ^ 1][0][1][0], &lds[p ^ 1][1][1][0],
                       ts, 1, K, tid);
            compute_phase(&lds[p][0][0][0], &lds[p][1][0][0], acc,
                          waveM, waveN, quad, l16, sl);
            asm volatile("s_waitcnt vmcnt(8)" ::: "memory");
            __builtin_amdgcn_s_barrier();
        }
        {   // phase B: compute kh1 of tile t; prefetch (t+2).kh0
            int ts = (t + 2 < NTt) ? (t + 2) : (NTt - 1);
            stage_half(gA, gB, &lds[p][0][0][0], &lds[p][1][0][0],
                       ts, 0, K, tid);
            compute_phase(&lds[p][0][1][0], &lds[p][1][1][0], acc,
                          waveM, waveN, quad, l16, sl);
            asm volatile("s_waitcnt vmcnt(8)" ::: "memory");
            __builtin_amdgcn_s_barrier();
        }
    }

    // epilogue: C/D layout col = lane&15 (N from B), row = quad*4 + reg (M)
    const size_t bm = (size_t)tm * GBM;
    const size_t bn = (size_t)tn * GBN;
    #pragma unroll
    for (int mi = 0; mi < 8; ++mi) {
        #pragma unroll
        for (int ni = 0; ni < 4; ++ni) {
            size_t col = bn + (size_t)waveN * 64 + ni * 16 + l16;
            #pragma unroll
            for (int r = 0; r < 4; ++r) {
                size_t row = bm + (size_t)waveM * 128 + mi * 16 + quad * 4 + r;
                C[row * N + col] = acc[mi][ni][r];
            }
        }
    }
}

// ---------------------------------------------------------------------------
extern "C" void kernel_launch(void* const* d_in, const int* in_sizes, int n_in,
                              void* d_out, int out_size, void* d_ws, size_t ws_size,
                              hipStream_t stream) {
    const float* x      = (const float*)d_in[0];
    const float* scale  = (const float*)d_in[1];
    const float* lnbias = (const float*)d_in[2];
    const float* W      = (const float*)d_in[3];

    const int H = in_sizes[1];                 // 2048
    const int M = in_sizes[0] / H;             // S*B = 8192
    const int F = in_sizes[3] / H;             // 8192

    float* z = (float*)d_out;                  // [M][F]
    float* y = z + (size_t)M * F;              // [M][H]

    unsigned short* Abf = (unsigned short*)d_ws;            // [M][H] bf16
    unsigned short* Btb = Abf + (size_t)M * H;              // [F][H] bf16

    ln_kernel<<<M, 256, 0, stream>>>(x, scale, lnbias, y, Abf, H);
    transpose_cast_kernel<<<dim3(F / 64, H / 64), 256, 0, stream>>>(W, Btb, H, F);
    gemm_bf16_8w<<<dim3((M / GBM) * (F / GBN)), 512, 0, stream>>>(Abf, Btb, z, M, F, H);
}